// Round 16
// baseline (677.623 us; speedup 1.0000x reference)
//
#include <hip/hip_runtime.h>
#include <hip/hip_bf16.h>

typedef __attribute__((ext_vector_type(4))) float f32x4;
typedef __attribute__((ext_vector_type(8))) short bf16x8;

#define NV 100000
#define NC 1024
#define NTILE 1563          // ceil(NV/64)
#define MB 1024             // mega grid: 4 blocks/CU x 256 CU, co-resident by construction
#define RB 128              // reducer blocks (phase 2)

__device__ __forceinline__ unsigned short f2bf(float f) {
  __hip_bfloat16 h = __float2bfloat16(f);
  return __builtin_bit_cast(unsigned short, h);
}
__device__ __forceinline__ float bf2f(unsigned short u) {
  return __builtin_bit_cast(float, ((unsigned)u) << 16);
}

// ---------------- K0: W1^T, W2^T, feat -> bf16; cent -> float4 ----------------
__global__ void k_prep(const float* __restrict__ W1, const float* __restrict__ W2,
                       const float* __restrict__ cent, const float* __restrict__ feat,
                       unsigned short* __restrict__ wt1, unsigned short* __restrict__ wt2,
                       float4* __restrict__ cent4, unsigned short* __restrict__ featb) {
  int gid = blockIdx.x * 256 + threadIdx.x;     // grid 64 -> 16384 threads
  if (gid < 128 * 128) {
    int j = gid >> 7, k = gid & 127;
    wt1[gid] = f2bf(W1[k * 128 + j]);   // W1 is [131][128]; rows >=128 multiply zeros
    wt2[gid] = f2bf(W2[k * 128 + j]);
  }
  if (gid < NC)
    cent4[gid] = make_float4(cent[gid * 3], cent[gid * 3 + 1], cent[gid * 3 + 2], 0.f);
  {
    int base = gid * 8;
    f32x4 a = *reinterpret_cast<const f32x4*>(feat + base);
    f32x4 b = *reinterpret_cast<const f32x4*>(feat + base + 4);
    bf16x8 o;
#pragma unroll
    for (int e = 0; e < 4; ++e) { o[e] = (short)f2bf(a[e]); o[4 + e] = (short)f2bf(b[e]); }
    *reinterpret_cast<bf16x8*>(featb + base) = o;
  }
}

// device-scope grid barrier (all MB blocks co-resident by construction)
__device__ __forceinline__ void gridbar(int* bar, int gen, int tid) {
  __syncthreads();
  if (tid == 0) {
    __threadfence();
    __hip_atomic_fetch_add(bar, 1, __ATOMIC_ACQ_REL, __HIP_MEMORY_SCOPE_AGENT);
    while (__hip_atomic_load(bar, __ATOMIC_ACQUIRE, __HIP_MEMORY_SCOPE_AGENT) < MB * gen)
      __builtin_amdgcn_s_sleep(16);
    __threadfence();
  }
  __syncthreads();
}

// ---------------- K1: persistent mega-kernel (interp+GEMM1+BN+GEMM2) ----------------
template <bool BF16H>
__global__ __launch_bounds__(256, 4) void k_mega(
    const float* __restrict__ vert, const float4* __restrict__ cent4,
    const unsigned short* __restrict__ featb, const unsigned short* __restrict__ wt1,
    const unsigned short* __restrict__ wt2, const float* __restrict__ b1,
    const float* __restrict__ b2, const float* __restrict__ gamma,
    const float* __restrict__ beta, float* __restrict__ HX,
    float* __restrict__ H1, unsigned short* __restrict__ H1B,
    float* __restrict__ partials, float* __restrict__ partials2,
    float* __restrict__ ash, int* __restrict__ bar) {
  __shared__ double rd2[64][13];
  __shared__ int    ridx[64][13];
  __shared__ float  wsum[4][128];
  __shared__ float  wsq[4][128];
  __shared__ __align__(16) float ashl[256];

  const int tid = threadIdx.x;
  const int lane = tid & 63;
  const int w = tid >> 6;
  const int jj = lane & 15, kg = lane >> 4;
  const int jb = __builtin_amdgcn_readfirstlane(w * 256);
  const float4* cb = cent4 + jb;

  for (int i = tid; i < 512; i += 256) { (&wsum[0][0])[i] = 0.f; (&wsq[0][0])[i] = 0.f; }

  // =================== phase 1: screen + refine + interp + GEMM1 + BN ===================
  for (int t = blockIdx.x; t < NTILE; t += MB) {
    const int vtx0 = t * 64;
    const int vtx = vtx0 + lane;
    const bool valid = vtx < NV;
    float vx = 0.f, vy = 0.f, vz = 0.f;
    if (valid) { vx = vert[vtx * 3]; vy = vert[vtx * 3 + 1]; vz = vert[vtx * 3 + 2]; }

    // ph2: branchless screening, 4 streams x top-3 of 64 each (r14-verified)
    unsigned p0 = ~0u, p1 = ~0u, p2 = ~0u;
    unsigned q0 = ~0u, q1 = ~0u, q2 = ~0u;
    unsigned r0 = ~0u, r1 = ~0u, r2 = ~0u;
    unsigned u0 = ~0u, u1 = ~0u, u2 = ~0u;
#pragma unroll 2
    for (int j = 0; j < 256; j += 4) {
      float4 c0 = cb[j], c1 = cb[j + 1], c2 = cb[j + 2], c3 = cb[j + 3];
      unsigned m, M;
      {
        float dx = vx - c0.x, dy = vy - c0.y, dz = vz - c0.z;
        float dd = fmaf(dz, dz, fmaf(dy, dy, dx * dx));
        unsigned k = (__builtin_bit_cast(unsigned, dd) & 0xFFFFFF00u) | (unsigned)j;
        m = min(k, p0); M = max(k, p0); p0 = m;
        m = min(M, p1); M = max(M, p1); p1 = m;
        p2 = min(M, p2);
      }
      {
        float dx = vx - c1.x, dy = vy - c1.y, dz = vz - c1.z;
        float dd = fmaf(dz, dz, fmaf(dy, dy, dx * dx));
        unsigned k = (__builtin_bit_cast(unsigned, dd) & 0xFFFFFF00u) | (unsigned)(j + 1);
        m = min(k, q0); M = max(k, q0); q0 = m;
        m = min(M, q1); M = max(M, q1); q1 = m;
        q2 = min(M, q2);
      }
      {
        float dx = vx - c2.x, dy = vy - c2.y, dz = vz - c2.z;
        float dd = fmaf(dz, dz, fmaf(dy, dy, dx * dx));
        unsigned k = (__builtin_bit_cast(unsigned, dd) & 0xFFFFFF00u) | (unsigned)(j + 2);
        m = min(k, r0); M = max(k, r0); r0 = m;
        m = min(M, r1); M = max(M, r1); r1 = m;
        r2 = min(M, r2);
      }
      {
        float dx = vx - c3.x, dy = vy - c3.y, dz = vz - c3.z;
        float dd = fmaf(dz, dz, fmaf(dy, dy, dx * dx));
        unsigned k = (__builtin_bit_cast(unsigned, dd) & 0xFFFFFF00u) | (unsigned)(j + 3);
        m = min(k, u0); M = max(k, u0); u0 = m;
        m = min(M, u1); M = max(M, u1); u1 = m;
        u2 = min(M, u2);
      }
    }

    // ph3a: per-thread f64 refine of its 12 candidates (np-identical, contract off)
    double e0, e1, e2; int x0, x1, x2;
    {
#pragma clang fp contract(off)
      const double dvx = (double)vx, dvy = (double)vy, dvz = (double)vz;
      const double sv64 = (dvx * dvx + dvy * dvy) + dvz * dvz;
      e0 = INFINITY; e1 = INFINITY; e2 = INFINITY;
      x0 = 0x7fffffff; x1 = 0x7fffffff; x2 = 0x7fffffff;
      const unsigned cand[12] = {p0, p1, p2, q0, q1, q2, r0, r1, r2, u0, u1, u2};
#pragma unroll
      for (int c = 0; c < 12; ++c) {
        int ix = jb + (int)(cand[c] & 0xFFu);
        float4 cf = cent4[ix];
        double cx = (double)cf.x, cy = (double)cf.y, cz = (double)cf.z;
        double sc2 = (cx * cx + cy * cy) + cz * cz;
        double dot = (dvx * cx + dvy * cy) + dvz * cz;
        double dd = (sv64 + sc2) - 2.0 * dot;
        if (dd < e2 || (dd == e2 && ix < x2)) {
          if (dd < e1 || (dd == e1 && ix < x1)) {
            e2 = e1; x2 = x1;
            if (dd < e0 || (dd == e0 && ix < x0)) { e1 = e0; x1 = x0; e0 = dd; x0 = ix; }
            else { e1 = dd; x1 = ix; }
          } else { e2 = dd; x2 = ix; }
        }
      }
    }
    __syncthreads();   // protect rd2/ridx from previous-tile readers
    rd2[lane][w * 3 + 0] = e0; rd2[lane][w * 3 + 1] = e1; rd2[lane][w * 3 + 2] = e2;
    ridx[lane][w * 3 + 0] = x0; ridx[lane][w * 3 + 1] = x1; ridx[lane][w * 3 + 2] = x2;
    __syncthreads();

    // ph3b: merge the 12 partials of this thread's GEMM vertex m
    const int m = w * 16 + jj;
    const int v = vtx0 + m;
    const bool valid2 = v < NV;
    float w0f, w1f, w2f;
    int nn0, nn1, nn2;
    {
      double f0 = INFINITY, f1 = INFINITY, f2 = INFINITY;
      int y0 = 0x7fffffff, y1 = 0x7fffffff, y2 = 0x7fffffff;
#pragma unroll
      for (int c = 0; c < 12; ++c) {
        double dd = rd2[m][c];
        int ix = ridx[m][c];
        if (dd < f2 || (dd == f2 && ix < y2)) {
          if (dd < f1 || (dd == f1 && ix < y1)) {
            f2 = f1; y2 = y1;
            if (dd < f0 || (dd == f0 && ix < y0)) { f1 = f0; y1 = y0; f0 = dd; y0 = ix; }
            else { f1 = dd; y1 = ix; }
          } else { f2 = dd; y2 = ix; }
        }
      }
      double s0 = sqrt(fmax(f0, 0.0)), s1 = sqrt(fmax(f1, 0.0)), s2 = sqrt(fmax(f2, 0.0));
      if (s0 == 0.0) { w0f = 1.f; w1f = 0.f; w2f = 0.f; }   // exact match: copy nearest
      else {
        double g0 = 1.0 / (s0 * s0), g1 = 1.0 / (s1 * s1), g2 = 1.0 / (s2 * s2);
        double rsd = 1.0 / (g0 + g1 + g2);
        w0f = (float)(g0 * rsd); w1f = (float)(g1 * rsd); w2f = (float)(g2 * rsd);
      }
      nn0 = (y0 < NC) ? y0 : 0;
      nn1 = (y1 < NC) ? y1 : 0;
      nn2 = (y2 < NC) ? y2 : 0;
    }

    // ph4: gathers -> interp -> B-frags
    bf16x8 bh[4];
#pragma unroll
    for (int ks = 0; ks < 4; ++ks) {
      const int off = ks * 32 + kg * 8;
      bf16x8 a = *reinterpret_cast<const bf16x8*>(featb + (size_t)nn0 * 128 + off);
      bf16x8 c = *reinterpret_cast<const bf16x8*>(featb + (size_t)nn1 * 128 + off);
      bf16x8 g = *reinterpret_cast<const bf16x8*>(featb + (size_t)nn2 * 128 + off);
      bf16x8 o;
#pragma unroll
      for (int e = 0; e < 8; ++e)
        o[e] = (short)f2bf(w0f * bf2f((unsigned short)a[e]) +
                           w1f * bf2f((unsigned short)c[e]) +
                           w2f * bf2f((unsigned short)g[e]));
      bh[ks] = o;
    }

    // ph5: swapped-operand MFMA + b1
    f32x4 acc[8];
#pragma unroll
    for (int n = 0; n < 8; ++n) acc[n] = (f32x4){0.f, 0.f, 0.f, 0.f};
#pragma unroll
    for (int ks = 0; ks < 4; ++ks) {
#pragma unroll
      for (int n = 0; n < 8; ++n) {
        bf16x8 aw = *reinterpret_cast<const bf16x8*>(
            wt1 + (n * 16 + jj) * 128 + ks * 32 + kg * 8);
        acc[n] = __builtin_amdgcn_mfma_f32_16x16x32_bf16(aw, bh[ks], acc[n], 0, 0, 0);
      }
    }

    // epilogue: h stores + BN partial accumulate (deterministic)
#pragma unroll
    for (int n = 0; n < 8; ++n) {
      f32x4 b1v = *reinterpret_cast<const f32x4*>(b1 + n * 16 + kg * 4);
      f32x4 h = acc[n] + b1v;
      if (valid2) {
        if (BF16H) {
          ushort4 pk = make_ushort4(f2bf(h[0]), f2bf(h[1]), f2bf(h[2]), f2bf(h[3]));
          *reinterpret_cast<ushort4*>(H1B + (size_t)v * 128 + n * 16 + kg * 4) = pk;
        } else {
          *reinterpret_cast<f32x4*>(H1 + (size_t)v * 128 + n * 16 + kg * 4) = h;
        }
      }
      f32x4 hz = valid2 ? h : (f32x4){0.f, 0.f, 0.f, 0.f};
#pragma unroll
      for (int r = 0; r < 4; ++r) {
        float a = hz[r], bq = hz[r] * hz[r];
        a += __shfl_xor(a, 1, 16); a += __shfl_xor(a, 2, 16);
        a += __shfl_xor(a, 4, 16); a += __shfl_xor(a, 8, 16);
        bq += __shfl_xor(bq, 1, 16); bq += __shfl_xor(bq, 2, 16);
        bq += __shfl_xor(bq, 4, 16); bq += __shfl_xor(bq, 8, 16);
        if (jj == 0) {
          wsum[w][n * 16 + kg * 4 + r] += a;
          wsq[w][n * 16 + kg * 4 + r] += bq;
        }
      }
    }
  }
  __syncthreads();
  if (tid < 128) {
    partials[(size_t)blockIdx.x * 256 + tid] =
        wsum[0][tid] + wsum[1][tid] + wsum[2][tid] + wsum[3][tid];
    partials[(size_t)blockIdx.x * 256 + 128 + tid] =
        wsq[0][tid] + wsq[1][tid] + wsq[2][tid] + wsq[3][tid];
  }
  gridbar(bar, 1, tid);

  // =================== phase 2: distributed partial reduction ===================
  if (blockIdx.x < RB) {
    double s = 0.0;
    for (int r = blockIdx.x; r < MB; r += RB)
      s += (double)__hip_atomic_load(&partials[(size_t)r * 256 + tid],
                                     __ATOMIC_RELAXED, __HIP_MEMORY_SCOPE_AGENT);
    partials2[(size_t)blockIdx.x * 256 + tid] = (float)s;
  }
  gridbar(bar, 2, tid);

  // =================== phase 3: block 0 finishes BN fold ===================
  if (blockIdx.x == 0) {
    double s = 0.0;
    for (int b = 0; b < RB; ++b)
      s += (double)__hip_atomic_load(&partials2[(size_t)b * 256 + tid],
                                     __ATOMIC_RELAXED, __HIP_MEMORY_SCOPE_AGENT);
    ((double*)rd2)[tid] = s;
    __syncthreads();
    if (tid < 128) {
      double mu  = ((double*)rd2)[tid] * (1.0 / (double)NV);
      double var = ((double*)rd2)[tid + 128] * (1.0 / (double)NV) - mu * mu;
      float af = gamma[tid] / sqrtf((float)var + 1e-5f);
      __hip_atomic_store(&ash[tid], af, __ATOMIC_RELAXED, __HIP_MEMORY_SCOPE_AGENT);
      __hip_atomic_store(&ash[128 + tid], beta[tid] - (float)mu * af,
                         __ATOMIC_RELAXED, __HIP_MEMORY_SCOPE_AGENT);
    }
  }
  gridbar(bar, 3, tid);

  // pull ash into LDS once (coherent loads), then GEMM2 over own tiles
  ashl[tid] = __hip_atomic_load(&ash[tid], __ATOMIC_RELAXED, __HIP_MEMORY_SCOPE_AGENT);
  __syncthreads();

  // =================== phase 4: GEMM2 on this block's tiles (L2-hot h1) ===================
  for (int t = blockIdx.x; t < NTILE; t += MB) {
    const int v = t * 64 + w * 16 + jj;
    const bool valid = v < NV;
    const size_t rb = (size_t)(valid ? v : NV - 1) * 128;

    bf16x8 bh[4];
#pragma unroll
    for (int ks = 0; ks < 4; ++ks) {
      const int k0 = ks * 32 + kg * 8;
      f32x4 sa0 = *reinterpret_cast<const f32x4*>(ashl + k0);
      f32x4 sa1 = *reinterpret_cast<const f32x4*>(ashl + k0 + 4);
      f32x4 sb0 = *reinterpret_cast<const f32x4*>(ashl + 128 + k0);
      f32x4 sb1 = *reinterpret_cast<const f32x4*>(ashl + 128 + k0 + 4);
      bf16x8 af;
      if (BF16H) {
        bf16x8 hv = *reinterpret_cast<const bf16x8*>(H1B + rb + k0);
#pragma unroll
        for (int e = 0; e < 4; ++e) {
          float h0 = bf2f((unsigned short)hv[e]);
          float h1 = bf2f((unsigned short)hv[4 + e]);
          af[e]     = (short)f2bf(fmaxf(h0 * sa0[e] + sb0[e], 0.f));
          af[4 + e] = (short)f2bf(fmaxf(h1 * sa1[e] + sb1[e], 0.f));
        }
      } else {
        f32x4 h0 = *reinterpret_cast<const f32x4*>(H1 + rb + k0);
        f32x4 h1 = *reinterpret_cast<const f32x4*>(H1 + rb + k0 + 4);
#pragma unroll
        for (int e = 0; e < 4; ++e) {
          af[e]     = (short)f2bf(fmaxf(h0[e] * sa0[e] + sb0[e], 0.f));
          af[4 + e] = (short)f2bf(fmaxf(h1[e] * sa1[e] + sb1[e], 0.f));
        }
      }
      bh[ks] = af;
    }

    f32x4 acc[8];
#pragma unroll
    for (int n = 0; n < 8; ++n) acc[n] = (f32x4){0.f, 0.f, 0.f, 0.f};
#pragma unroll
    for (int ks = 0; ks < 4; ++ks) {
#pragma unroll
      for (int n = 0; n < 8; ++n) {
        bf16x8 aw = *reinterpret_cast<const bf16x8*>(
            wt2 + (n * 16 + jj) * 128 + ks * 32 + kg * 8);
        acc[n] = __builtin_amdgcn_mfma_f32_16x16x32_bf16(aw, bh[ks], acc[n], 0, 0, 0);
      }
    }
    if (valid) {
#pragma unroll
      for (int n = 0; n < 8; ++n) {
        f32x4 b2v = *reinterpret_cast<const f32x4*>(b2 + n * 16 + kg * 4);
        f32x4 o = acc[n] + b2v;
        *reinterpret_cast<f32x4*>(HX + (size_t)v * 128 + n * 16 + kg * 4) = o;
      }
    }
  }
}

extern "C" void kernel_launch(void* const* d_in, const int* in_sizes, int n_in,
                              void* d_out, int out_size, void* d_ws, size_t ws_size,
                              hipStream_t stream) {
  const float* vert  = (const float*)d_in[0];
  const float* cent  = (const float*)d_in[1];
  const float* feat  = (const float*)d_in[2];
  const float* W1    = (const float*)d_in[3];
  const float* b1    = (const float*)d_in[4];
  const float* gamma = (const float*)d_in[5];
  const float* beta  = (const float*)d_in[6];
  const float* W2    = (const float*)d_in[7];
  const float* b2    = (const float*)d_in[8];
  float* out = (float*)d_out;
  char* ws = (char*)d_ws;

  float* partials  = (float*)ws;                                       // 1 MB
  float* partials2 = (float*)(ws + (1u << 20));                        // 128 KB
  unsigned short* wt1 = (unsigned short*)(ws + (1u << 20) + 256 * 1024);  // 32 KB
  unsigned short* wt2 = wt1 + 128 * 128;                                  // 32 KB
  float* ash = (float*)(ws + (1u << 20) + 384 * 1024);                 // 1 KB
  int* bar = (int*)(ws + (1u << 20) + 448 * 1024);                     // 64 B
  float4* cent4 = (float4*)(ws + (1u << 20) + 512 * 1024);             // 16 KB
  unsigned short* featb = (unsigned short*)(ws + (1u << 20) + 640 * 1024); // 256 KB
  unsigned short* h1b = (unsigned short*)(ws + (2u << 20));            // 25.6 MB
  const bool bf16h = ws_size >= (size_t)(2u << 20) + (size_t)NV * 128 * 2 + (1u << 16);

  k_prep<<<64, 256, 0, stream>>>(W1, W2, cent, feat, wt1, wt2, cent4, featb);
  hipMemsetAsync(bar, 0, 64, stream);
  if (bf16h) {
    k_mega<true><<<MB, 256, 0, stream>>>(vert, cent4, featb, wt1, wt2, b1, b2,
                                         gamma, beta, out, out, h1b,
                                         partials, partials2, ash, bar);
  } else {
    k_mega<false><<<MB, 256, 0, stream>>>(vert, cent4, featb, wt1, wt2, b1, b2,
                                          gamma, beta, out, out, h1b,
                                          partials, partials2, ash, bar);
  }
}